// Round 5
// baseline (319.666 us; speedup 1.0000x reference)
//
#include <hip/hip_runtime.h>
#include <math.h>

typedef __attribute__((ext_vector_type(8))) __bf16 bf16x8;
typedef __attribute__((ext_vector_type(4))) float f32x4;

__device__ __forceinline__ float act_lrelu(float x) { return x >= 0.0f ? x : 0.01f * x; }
__device__ __forceinline__ float act_gelu(float x) { return 0.5f * x * (1.0f + erff(x * 0.7071067811865475f)); }
__device__ __forceinline__ ushort f2bf(float f) {
    unsigned u = __builtin_bit_cast(unsigned, f);
    u += 0x7fffu + ((u >> 16) & 1u);   // RTNE
    return (ushort)(u >> 16);
}

// ---------------------------------------------------------------------------
// convert: all square weights + wf1 -> bf16 into Wdst.
// layout (ushort idx): wqc@0 (131072), wq1@131072, wq2@147456, wk1@163840,
// wk2@180224, wv1@196608, wv2@212992, wf2@229376 (each 16384), wf1@245760 (131072)
// grid 92, block 256; 4096 elems/block.
__global__ __launch_bounds__(256) void convert_kernel(
    const float* __restrict__ wqc, const float* __restrict__ wq1,
    const float* __restrict__ wq2, const float* __restrict__ wk1,
    const float* __restrict__ wk2, const float* __restrict__ wv1,
    const float* __restrict__ wv2, const float* __restrict__ wf2,
    const float* __restrict__ wf1, ushort* __restrict__ Wdst)
{
    const int tid = threadIdx.x;
    #pragma unroll
    for (int p = 0; p < 4; ++p) {
        const int lin = blockIdx.x * 4096 + p * 1024 + tid * 4;
        const float* s;
        if (lin < 131072) s = wqc + lin;
        else if (lin < 245760) {
            const int m = (lin - 131072) >> 14, idx = (lin - 131072) & 16383;
            s = (m == 0) ? wq1 + idx : (m == 1) ? wq2 + idx : (m == 2) ? wk1 + idx :
                (m == 3) ? wk2 + idx : (m == 4) ? wv1 + idx : (m == 5) ? wv2 + idx
                         : wf2 + idx;
        } else s = wf1 + (lin - 245760);
        const float4 v = *(const float4*)s;
        ushort4 u; u.x = f2bf(v.x); u.y = f2bf(v.y); u.z = f2bf(v.z); u.w = f2bf(v.w);
        *(ushort4*)&Wdst[lin] = u;
    }
}

// ---------------------------------------------------------------------------
// transpose+cast: IN [bz][C][N] f32  ->  OUT [bz][N][C] bf16
__global__ __launch_bounds__(256) void transpose_cast(
    const float* __restrict__ IN, ushort* __restrict__ OUTb, int C, int N)
{
    __shared__ float T[64][68];
    const int tid = threadIdx.x;
    const int r = tid >> 4, c4 = (tid & 15) * 4;
    const int n0 = blockIdx.x * 64, c0 = blockIdx.y * 64;
    const size_t ib = (size_t)blockIdx.z * C * N;
    const size_t ob = (size_t)blockIdx.z * N * C;
    #pragma unroll
    for (int p = 0; p < 4; ++p) {
        const int cl = r + p * 16;
        const float4 v = *(const float4*)&IN[ib + (size_t)(c0 + cl) * N + n0 + c4];
        *(float4*)&T[cl][c4] = v;
    }
    __syncthreads();
    #pragma unroll
    for (int p = 0; p < 4; ++p) {
        const int nl = r + p * 16;
        ushort4 u;
        u.x = f2bf(T[c4 + 0][nl]);
        u.y = f2bf(T[c4 + 1][nl]);
        u.z = f2bf(T[c4 + 2][nl]);
        u.w = f2bf(T[c4 + 3][nl]);
        *(ushort4*)&OUTb[ob + (size_t)(n0 + nl) * C + c0 + c4] = u;
    }
}

// ---------------------------------------------------------------------------
// swizzled-LDS MFMA helpers. W LDS layout: [128][128] ushort, element (r,c)
// stored at r*128 + (c ^ ((r&7)<<3)).
__device__ __forceinline__ void stage_wbf(const ushort* __restrict__ Wg,
                                          ushort* Wl, int tid)
{
    #pragma unroll
    for (int it = 0; it < 8; ++it) {
        const int lin = (tid + it * 256) * 8;
        const int r = lin >> 7, c = lin & 127;
        const bf16x8 v = *(const bf16x8*)&Wg[lin];
        *(bf16x8*)&Wl[r * 128 + (c ^ ((r & 7) << 3))] = v;
    }
}

__device__ __forceinline__ void layer8swz(const bf16x8 a[4], const ushort* Wl,
                                          f32x4 acc[8], int l15, int lk8)
{
    const int sx = (l15 & 7) << 3;
    #pragma unroll
    for (int ds = 0; ds < 4; ++ds) {
        const int cb = (ds * 32 + lk8) ^ sx;
        #pragma unroll
        for (int nt = 0; nt < 8; ++nt) {
            const bf16x8 b = *(const bf16x8*)&Wl[(nt * 16 + l15) * 128 + cb];
            acc[nt] = __builtin_amdgcn_mfma_f32_16x16x32_bf16(a[ds], b, acc[nt], 0, 0, 0);
        }
    }
}

template <int ACT>
__device__ __forceinline__ void retile_swz(const f32x4 acc[8], const float bias[8],
                                           ushort* tlw, int l15, int lr4, int lk8,
                                           bf16x8 aout[4])
{
    #pragma unroll
    for (int nt = 0; nt < 8; ++nt)
        #pragma unroll
        for (int j = 0; j < 4; ++j) {
            float v = acc[nt][j] + bias[nt];
            if constexpr (ACT == 1) v = act_lrelu(v);
            if constexpr (ACT == 2) v = act_gelu(v);
            const int row = lr4 + j;
            tlw[row * 128 + ((nt * 16 + l15) ^ ((row & 7) << 3))] = f2bf(v);
        }
    const int sx = (l15 & 7) << 3;
    #pragma unroll
    for (int ds = 0; ds < 4; ++ds)
        aout[ds] = *(const bf16x8*)&tlw[l15 * 128 + ((ds * 32 + lk8) ^ sx)];
}

// ---------------------------------------------------------------------------
// wcomb: blocks 0..7: Wcomb_h[j][d] = sum_o wf1[j][h*128+o] * wo[o][d] via MFMA
//        block 8: bconst[j] = bf1[j] + sum_k wf1[j][k]*bo[k&127]
__global__ __launch_bounds__(256) void wcomb_kernel(
    const ushort* __restrict__ wf1b,   // [128][1024] bf16
    const ushort* __restrict__ woTb,   // [128][128] bf16: woT[d][o]
    const float* __restrict__ wf1, const float* __restrict__ bo,
    const float* __restrict__ bf1,
    ushort* __restrict__ Wcomb, float* __restrict__ bconst)
{
    __shared__ ushort Wl[128 * 128];
    __shared__ float sm[256];
    const int tid = threadIdx.x, lane = tid & 63, w = tid >> 6;
    const int l15 = lane & 15, lk8 = (lane >> 4) * 8, lr4 = (lane >> 4) * 4;
    const int blk = blockIdx.x;
    if (blk < 8) {
        stage_wbf(woTb, Wl, tid);
        __syncthreads();
        const f32x4 z = {0.f, 0.f, 0.f, 0.f};
        #pragma unroll
        for (int rf = 0; rf < 2; ++rf) {
            const int row = w * 32 + rf * 16;
            bf16x8 a[4];
            #pragma unroll
            for (int ds = 0; ds < 4; ++ds)
                a[ds] = *(const bf16x8*)&wf1b[(size_t)(row + l15) * 1024 + blk * 128 + ds * 32 + lk8];
            f32x4 acc[8];
            #pragma unroll
            for (int i = 0; i < 8; ++i) acc[i] = z;
            layer8swz(a, Wl, acc, l15, lk8);
            #pragma unroll
            for (int nt = 0; nt < 8; ++nt)
                #pragma unroll
                for (int j = 0; j < 4; ++j)
                    Wcomb[blk * 16384 + (row + lr4 + j) * 128 + nt * 16 + l15] =
                        f2bf(acc[nt][j]);
        }
    } else {
        const int j = tid & 127, kh = tid >> 7;
        float acc = (kh == 0) ? bf1[j] : 0.f;
        for (int k = kh * 512; k < kh * 512 + 512; ++k)
            acc += wf1[j * 1024 + k] * bo[k & 127];
        sm[tid] = acc;
        __syncthreads();
        if (tid < 128) bconst[j] = sm[j] + sm[j + 128];
    }
}

// ---------------------------------------------------------------------------
// mlp1: Y = X @ W_head^T + B_head (no act). 128 rows/block.
template <bool QMAP>
__global__ __launch_bounds__(256) void mlp1v(
    const ushort* __restrict__ X, const ushort* __restrict__ Wbf,
    const float* __restrict__ Bf, ushort* __restrict__ Y)
{
    __shared__ ushort Wl[128 * 128];
    const int tid = threadIdx.x, lane = tid & 63, w = tid >> 6;
    const int l15 = lane & 15, lk8 = (lane >> 4) * 8, lr4 = (lane >> 4) * 4;
    const int head = (blockIdx.x >> 3) & 7;
    stage_wbf(Wbf + head * 16384, Wl, tid);
    float b0[8];
    #pragma unroll
    for (int nt = 0; nt < 8; ++nt) b0[nt] = Bf[head * 128 + nt * 16 + l15];

    const int m0 = blockIdx.x * 128 + w * 32;
    bf16x8 a0[4], a1[4];
    #pragma unroll
    for (int ds = 0; ds < 4; ++ds) {
        int r0 = m0 + l15, r1 = m0 + 16 + l15;
        if constexpr (QMAP) { r0 = (r0 >> 13) * 1024 + (r0 & 1023); r1 = (r1 >> 13) * 1024 + (r1 & 1023); }
        a0[ds] = *(const bf16x8*)(X + (size_t)r0 * 128 + ds * 32 + lk8);
        a1[ds] = *(const bf16x8*)(X + (size_t)r1 * 128 + ds * 32 + lk8);
    }
    __syncthreads();
    const f32x4 z = {0.f, 0.f, 0.f, 0.f};
    #pragma unroll
    for (int rf = 0; rf < 2; ++rf) {
        f32x4 acc[8];
        #pragma unroll
        for (int i = 0; i < 8; ++i) acc[i] = z;
        layer8swz(rf ? a1 : a0, Wl, acc, l15, lk8);
        const int row = m0 + rf * 16;
        #pragma unroll
        for (int nt = 0; nt < 8; ++nt)
            #pragma unroll
            for (int j = 0; j < 4; ++j)
                Y[(size_t)(row + lr4 + j) * 128 + nt * 16 + l15] = f2bf(acc[nt][j] + b0[nt]);
    }
}

// ---------------------------------------------------------------------------
// mlp2: Y = act2(act1(X@W1^T+b1)@W2^T+b2). 128 rows/block. bf16 weights.
template <int ACT1, int ACT2, bool OUTT>
__global__ __launch_bounds__(256) void mlp2v(
    const ushort* __restrict__ X,
    const ushort* __restrict__ W1bf, const float* __restrict__ B1,
    const ushort* __restrict__ W2bf, const float* __restrict__ B2,
    ushort* __restrict__ Y)
{
    __shared__ ushort W1l[128 * 128], W2l[128 * 128];
    __shared__ ushort tl[4][16 * 128];
    const int tid = threadIdx.x, lane = tid & 63, w = tid >> 6;
    const int l15 = lane & 15, lk8 = (lane >> 4) * 8, lr4 = (lane >> 4) * 4;
    stage_wbf(W1bf, W1l, tid);
    stage_wbf(W2bf, W2l, tid);
    float b1[8], b2[8];
    #pragma unroll
    for (int nt = 0; nt < 8; ++nt) { b1[nt] = B1[nt * 16 + l15]; b2[nt] = B2[nt * 16 + l15]; }

    const int m0 = blockIdx.x * 128 + w * 32;
    bf16x8 a0[4], a1[4];
    #pragma unroll
    for (int ds = 0; ds < 4; ++ds) {
        a0[ds] = *(const bf16x8*)(X + (size_t)(m0 + l15) * 128 + ds * 32 + lk8);
        a1[ds] = *(const bf16x8*)(X + (size_t)(m0 + 16 + l15) * 128 + ds * 32 + lk8);
    }
    __syncthreads();
    const f32x4 z = {0.f, 0.f, 0.f, 0.f};
    #pragma unroll
    for (int rf = 0; rf < 2; ++rf) {
        const int row = m0 + rf * 16;
        f32x4 acc[8];
        #pragma unroll
        for (int i = 0; i < 8; ++i) acc[i] = z;
        layer8swz(rf ? a1 : a0, W1l, acc, l15, lk8);
        bf16x8 a2[4];
        retile_swz<ACT1>(acc, b1, tl[w], l15, lr4, lk8, a2);
        f32x4 acc2[8];
        #pragma unroll
        for (int i = 0; i < 8; ++i) acc2[i] = z;
        layer8swz(a2, W2l, acc2, l15, lk8);
        if constexpr (!OUTT) {
            #pragma unroll
            for (int nt = 0; nt < 8; ++nt)
                #pragma unroll
                for (int j = 0; j < 4; ++j) {
                    float v = acc2[nt][j] + b2[nt];
                    if constexpr (ACT2 == 1) v = act_lrelu(v);
                    if constexpr (ACT2 == 2) v = act_gelu(v);
                    Y[(size_t)(row + lr4 + j) * 128 + nt * 16 + l15] = f2bf(v);
                }
        } else {
            const int R0 = row + lr4;
            const int bh = R0 >> 11, key = R0 & 2047;
            #pragma unroll
            for (int nt = 0; nt < 8; ++nt) {
                ushort4 pk;
                #pragma unroll
                for (int j = 0; j < 4; ++j) {
                    float v = acc2[nt][j] + b2[nt];
                    if constexpr (ACT2 == 1) v = act_lrelu(v);
                    if constexpr (ACT2 == 2) v = act_gelu(v);
                    (&pk.x)[j] = f2bf(v);
                }
                *(ushort4*)&Y[((size_t)bh * 128 + nt * 16 + l15) * 2048 + key] = pk;
            }
        }
    }
}

// ---------------------------------------------------------------------------
// outpath: y = lrelu(sum_h enh_h @ Wcomb_h^T + bconst); out = lrelu(y@wf2^T+bf2)
__global__ __launch_bounds__(256) void outpath2(
    const ushort* __restrict__ E, const ushort* __restrict__ Wcomb,
    const float* __restrict__ bconst, const ushort* __restrict__ Wf2bf,
    const float* __restrict__ Bf2, float* __restrict__ OUT)
{
    __shared__ ushort Wc[128 * 128], W2l[128 * 128];
    __shared__ ushort tl[4][16 * 128];
    const int tid = threadIdx.x, lane = tid & 63, w = tid >> 6;
    const int l15 = lane & 15, lk8 = (lane >> 4) * 8, lr4 = (lane >> 4) * 4;
    const int b = blockIdx.x >> 4;
    const int m0 = (blockIdx.x & 15) * 64;
    stage_wbf(Wf2bf, W2l, tid);
    float bc[8], b2[8];
    #pragma unroll
    for (int nt = 0; nt < 8; ++nt) { bc[nt] = bconst[nt * 16 + l15]; b2[nt] = Bf2[nt * 16 + l15]; }

    const f32x4 z = {0.f, 0.f, 0.f, 0.f};
    f32x4 yacc[8];
    #pragma unroll
    for (int i = 0; i < 8; ++i) yacc[i] = z;

    bf16x8 a[4], an[4];
    auto loadE = [&](int h, bf16x8 dst[4]) {
        const size_t er = ((size_t)((b * 8 + h) * 1024) + m0 + w * 16 + l15) * 128;
        #pragma unroll
        for (int ds = 0; ds < 4; ++ds) dst[ds] = *(const bf16x8*)(E + er + ds * 32 + lk8);
    };
    loadE(0, a);
    #pragma unroll
    for (int ds = 0; ds < 4; ++ds) an[ds] = a[ds];

    for (int h = 0; h < 8; ++h) {
        __syncthreads();
        stage_wbf(Wcomb + h * 16384, Wc, tid);
        if (h < 7) loadE(h + 1, an);
        __syncthreads();
        layer8swz(a, Wc, yacc, l15, lk8);
        #pragma unroll
        for (int ds = 0; ds < 4; ++ds) a[ds] = an[ds];
    }
    bf16x8 a3[4];
    retile_swz<1>(yacc, bc, tl[w], l15, lr4, lk8, a3);
    f32x4 oacc[8];
    #pragma unroll
    for (int i = 0; i < 8; ++i) oacc[i] = z;
    layer8swz(a3, W2l, oacc, l15, lk8);
    #pragma unroll
    for (int nt = 0; nt < 8; ++nt)
        #pragma unroll
        for (int j = 0; j < 4; ++j)
            OUT[((size_t)b * 1024 + m0 + w * 16 + lr4 + j) * 128 + nt * 16 + l15] =
                act_lrelu(oacc[nt][j] + b2[nt]);
}

// ---------------------------------------------------------------------------
// bf16 MFMA flash attention (unchanged).
__global__ __launch_bounds__(256, 2) void flash_attn_bf16(
    const ushort* __restrict__ Q, const ushort* __restrict__ Kx,
    const ushort* __restrict__ Vt, ushort* __restrict__ O)
{
    constexpr float SCALE = 0.08838834764831845f;
    const int bh = blockIdx.y;
    const int m0 = blockIdx.x * 64;
    const int tid = threadIdx.x;
    const int lane = tid & 63, w = tid >> 6;
    const int l15 = lane & 15, lk8 = (lane >> 4) * 8, lr4 = (lane >> 4) * 4;

    __shared__ ushort K_lds[2][64 * 136];
    __shared__ ushort V_lds[2][128 * 72];
    __shared__ ushort P_lds[64 * 72];

    const ushort* Qb = Q + (size_t)bh * 1024 * 128;
    const ushort* Kb = Kx + (size_t)bh * 2048 * 128;
    const ushort* Vb = Vt + (size_t)bh * 128 * 2048;

    bf16x8 qf[4];
    {
        const int row = m0 + w * 16 + l15;
        #pragma unroll
        for (int ds = 0; ds < 4; ++ds)
            qf[ds] = *(const bf16x8*)(Qb + (size_t)row * 128 + ds * 32 + lk8);
    }

    const int kr = tid >> 4, kc = (tid & 15) * 8;
    const int vr = tid >> 3, vc = (tid & 7) * 8;
    bf16x8 kreg[4], vreg[4];
    #pragma unroll
    for (int it = 0; it < 4; ++it) {
        kreg[it] = *(const bf16x8*)(Kb + (size_t)(kr + it * 16) * 128 + kc);
        vreg[it] = *(const bf16x8*)(Vb + (size_t)(vr + it * 32) * 2048 + vc);
    }
    #pragma unroll
    for (int it = 0; it < 4; ++it) {
        *(bf16x8*)&K_lds[0][(kr + it * 16) * 136 + kc] = kreg[it];
        *(bf16x8*)&V_lds[0][(vr + it * 32) * 72 + vc] = vreg[it];
    }
    __syncthreads();

    f32x4 oacc[8];
    #pragma unroll
    for (int i = 0; i < 8; ++i) oacc[i] = f32x4{0.f, 0.f, 0.f, 0.f};
    float mrun[4] = {-1e30f, -1e30f, -1e30f, -1e30f};
    float lrun[4] = {0.f, 0.f, 0.f, 0.f};
    int cur = 0;

    for (int nt = 0; nt < 32; ++nt) {
        if (nt < 31) {
            const int n1 = (nt + 1) * 64;
            #pragma unroll
            for (int it = 0; it < 4; ++it) {
                kreg[it] = *(const bf16x8*)(Kb + (size_t)(n1 + kr + it * 16) * 128 + kc);
                vreg[it] = *(const bf16x8*)(Vb + (size_t)(vr + it * 32) * 2048 + n1 + vc);
            }
        }
        const ushort* Kc = &K_lds[cur][0];
        const ushort* Vc = &V_lds[cur][0];

        f32x4 s[4];
        #pragma unroll
        for (int i = 0; i < 4; ++i) s[i] = f32x4{0.f, 0.f, 0.f, 0.f};
        __builtin_amdgcn_s_setprio(1);
        #pragma unroll
        for (int ds = 0; ds < 4; ++ds)
            #pragma unroll
            for (int ct = 0; ct < 4; ++ct) {
                const bf16x8 bfr = *(const bf16x8*)&Kc[(ct * 16 + l15) * 136 + ds * 32 + lk8];
                s[ct] = __builtin_amdgcn_mfma_f32_16x16x32_bf16(qf[ds], bfr, s[ct], 0, 0, 0);
            }
        __builtin_amdgcn_s_setprio(0);

        float mx[4], p[4][4], fsc[4];
        #pragma unroll
        for (int j = 0; j < 4; ++j)
            mx[j] = fmaxf(fmaxf(s[0][j], s[1][j]), fmaxf(s[2][j], s[3][j])) * SCALE;
        #pragma unroll
        for (int off = 1; off <= 8; off <<= 1)
            #pragma unroll
            for (int j = 0; j < 4; ++j)
                mx[j] = fmaxf(mx[j], __shfl_xor(mx[j], off));
        #pragma unroll
        for (int j = 0; j < 4; ++j) {
            const float mnew = fmaxf(mrun[j], mx[j]);
            fsc[j] = __expf(mrun[j] - mnew);
            mrun[j] = mnew;
            float sum = 0.f;
            #pragma unroll
            for (int ct = 0; ct < 4; ++ct) {
                const float e = __expf(s[ct][j] * SCALE - mnew);
                p[ct][j] = e;
                sum += e;
            }
            sum += __shfl_xor(sum, 1); sum += __shfl_xor(sum, 2);
            sum += __shfl_xor(sum, 4); sum += __shfl_xor(sum, 8);
            lrun[j] = lrun[j] * fsc[j] + sum;
        }
        #pragma unroll
        for (int j = 0; j < 4; ++j) {
            const int prow = w * 16 + lr4 + j;
            #pragma unroll
            for (int ct = 0; ct < 4; ++ct)
                P_lds[prow * 72 + ct * 16 + l15] = f2bf(p[ct][j]);
        }
        #pragma unroll
        for (int dt = 0; dt < 8; ++dt)
            #pragma unroll
            for (int j = 0; j < 4; ++j)
                oacc[dt][j] *= fsc[j];

        __builtin_amdgcn_s_setprio(1);
        #pragma unroll
        for (int ks = 0; ks < 2; ++ks) {
            const bf16x8 pa = *(const bf16x8*)&P_lds[(w * 16 + l15) * 72 + ks * 32 + lk8];
            #pragma unroll
            for (int dt = 0; dt < 8; ++dt) {
                const bf16x8 vb = *(const bf16x8*)&Vc[(dt * 16 + l15) * 72 + ks * 32 + lk8];
                oacc[dt] = __builtin_amdgcn_mfma_f32_16x16x32_bf16(pa, vb, oacc[dt], 0, 0, 0);
            }
        }
        __builtin_amdgcn_s_setprio(0);

        if (nt < 31) {
            const int nxt = cur ^ 1;
            #pragma unroll
            for (int it = 0; it < 4; ++it) {
                *(bf16x8*)&K_lds[nxt][(kr + it * 16) * 136 + kc] = kreg[it];
                *(bf16x8*)&V_lds[nxt][(vr + it * 32) * 72 + vc] = vreg[it];
            }
        }
        __syncthreads();
        cur ^= 1;
    }

    ushort* Ob = O + (size_t)bh * 1024 * 128;
    #pragma unroll
    for (int j = 0; j < 4; ++j) {
        const float inv = 1.0f / lrun[j];
        const int row = m0 + w * 16 + lr4 + j;
        #pragma unroll
        for (int dt = 0; dt < 8; ++dt)
            Ob[(size_t)row * 128 + dt * 16 + l15] = f2bf(oacc[dt][j] * inv);
    }
}

// ---------------------------------------------------------------------------
extern "C" void kernel_launch(void* const* d_in, const int* in_sizes, int n_in,
                              void* d_out, int out_size, void* d_ws, size_t ws_size,
                              hipStream_t stream)
{
    (void)in_sizes; (void)n_in; (void)out_size; (void)ws_size;
    const float* query = (const float*)d_in[0];
    const float* fts   = (const float*)d_in[1];
    const float* wqc = (const float*)d_in[2];
    const float* bqc = (const float*)d_in[3];
    const float* wq1 = (const float*)d_in[4];
    const float* bq1 = (const float*)d_in[5];
    const float* wq2 = (const float*)d_in[6];
    const float* bq2 = (const float*)d_in[7];
    const float* wk1 = (const float*)d_in[8];
    const float* bk1 = (const float*)d_in[9];
    const float* wk2 = (const float*)d_in[10];
    const float* bk2 = (const float*)d_in[11];
    const float* wv1 = (const float*)d_in[12];
    const float* bv1 = (const float*)d_in[13];
    const float* wv2 = (const float*)d_in[14];
    const float* bv2 = (const float*)d_in[15];
    const float* wo  = (const float*)d_in[16];
    const float* bo  = (const float*)d_in[17];
    const float* wf1 = (const float*)d_in[18];
    const float* bf1 = (const float*)d_in[19];
    const float* wf2 = (const float*)d_in[20];
    const float* bf2 = (const float*)d_in[21];
    float* out = (float*)d_out;

    // ws layout (~78 MB)
    char* ws = (char*)d_ws;
    ushort* ftb    = (ushort*)(ws + 0LL);          // 16 MB [32][2048][128]
    ushort* queryT = (ushort*)(ws + 16777216LL);   //  1 MB [4][1024][128]
    ushort* qh     = (ushort*)(ws + 17825792LL);   //  8 MB [32][1024][128]
    ushort* qbuf   = (ushort*)(ws + 26214400LL);   //  8 MB [32][1024][128]
    ushort* kbuf   = (ushort*)(ws + 34603008LL);   // 16 MB [32][2048][128]
    ushort* vbufT  = (ushort*)(ws + 51380224LL);   // 16 MB [32][128][2048]
    ushort* enh    = (ushort*)(ws + 68157440LL);   //  8 MB [32][1024][128]
    ushort* Wbf    = (ushort*)(ws + 76546048LL);   // 736 KB converted weights (incl wf1)
    ushort* Wcomb  = (ushort*)(ws + 77299712LL);   // 256 KB [8][128][128]
    float*  bconst = (float*) (ws + 77561856LL);   // 512 B
    ushort* woTb   = (ushort*)(ws + 77562368LL);   // 32 KB [128][128]

    // bf16 weight sub-offsets (ushort units)
    ushort* wqc_b = Wbf + 0;
    ushort* wq1_b = Wbf + 131072;
    ushort* wq2_b = Wbf + 147456;
    ushort* wk1_b = Wbf + 163840;
    ushort* wk2_b = Wbf + 180224;
    ushort* wv1_b = Wbf + 196608;
    ushort* wv2_b = Wbf + 212992;
    ushort* wf2_b = Wbf + 229376;
    ushort* wf1_b = Wbf + 245760;

    convert_kernel<<<92, 256, 0, stream>>>(wqc, wq1, wq2, wk1, wk2, wv1, wv2,
                                           wf2, wf1, Wbf);
    transpose_cast<<<dim3(2, 2, 1), 256, 0, stream>>>(wo, woTb, 128, 128);
    wcomb_kernel<<<9, 256, 0, stream>>>(wf1_b, woTb, wf1, bo, bf1, Wcomb, bconst);
    transpose_cast<<<dim3(32, 2, 32), 256, 0, stream>>>(fts, ftb, 128, 2048);
    transpose_cast<<<dim3(16, 2, 4), 256, 0, stream>>>(query, queryT, 128, 1024);
    // q-path
    mlp1v<true><<<256, 256, 0, stream>>>(queryT, wqc_b, bqc, qh);
    mlp2v<1, 2, false><<<256, 256, 0, stream>>>(qh, wq1_b, bq1, wq2_b, bq2, qbuf);
    // k-path / v-path
    mlp2v<1, 2, false><<<512, 256, 0, stream>>>(ftb, wk1_b, bk1, wk2_b, bk2, kbuf);
    mlp2v<1, 2, true><<<512, 256, 0, stream>>>(ftb, wv1_b, bv1, wv2_b, bv2, vbufT);
    // attention
    flash_attn_bf16<<<dim3(16, 32), 256, 0, stream>>>(qbuf, kbuf, vbufT, enh);
    // fused proj_out+concat+final MLP
    outpath2<<<64, 256, 0, stream>>>(enh, Wcomb, bconst, wf2_b, bf2, out);
}

// Round 6
// 243.991 us; speedup vs baseline: 1.3102x; 1.3102x over previous
//
#include <hip/hip_runtime.h>
#include <math.h>

typedef __attribute__((ext_vector_type(8))) __bf16 bf16x8;
typedef __attribute__((ext_vector_type(4))) float f32x4;

__device__ __forceinline__ float act_lrelu(float x) { return x >= 0.0f ? x : 0.01f * x; }
__device__ __forceinline__ float act_gelu(float x) { return 0.5f * x * (1.0f + erff(x * 0.7071067811865475f)); }
__device__ __forceinline__ ushort f2bf(float f) {
    unsigned u = __builtin_bit_cast(unsigned, f);
    u += 0x7fffu + ((u >> 16) & 1u);   // RTNE
    return (ushort)(u >> 16);
}

// ---------------------------------------------------------------------------
// convert: all square weights + wf1 -> bf16 into Wdst. grid 92.
__global__ __launch_bounds__(256) void convert_kernel(
    const float* __restrict__ wqc, const float* __restrict__ wq1,
    const float* __restrict__ wq2, const float* __restrict__ wk1,
    const float* __restrict__ wk2, const float* __restrict__ wv1,
    const float* __restrict__ wv2, const float* __restrict__ wf2,
    const float* __restrict__ wf1, ushort* __restrict__ Wdst)
{
    const int tid = threadIdx.x;
    #pragma unroll
    for (int p = 0; p < 4; ++p) {
        const int lin = blockIdx.x * 4096 + p * 1024 + tid * 4;
        const float* s;
        if (lin < 131072) s = wqc + lin;
        else if (lin < 245760) {
            const int m = (lin - 131072) >> 14, idx = (lin - 131072) & 16383;
            s = (m == 0) ? wq1 + idx : (m == 1) ? wq2 + idx : (m == 2) ? wk1 + idx :
                (m == 3) ? wk2 + idx : (m == 4) ? wv1 + idx : (m == 5) ? wv2 + idx
                         : wf2 + idx;
        } else s = wf1 + (lin - 245760);
        const float4 v = *(const float4*)s;
        ushort4 u; u.x = f2bf(v.x); u.y = f2bf(v.y); u.z = f2bf(v.z); u.w = f2bf(v.w);
        *(ushort4*)&Wdst[lin] = u;
    }
}

// ---------------------------------------------------------------------------
// transpose+cast: IN [bz][C][N] f32  ->  OUT [bz][N][C] bf16
__global__ __launch_bounds__(256) void transpose_cast(
    const float* __restrict__ IN, ushort* __restrict__ OUTb, int C, int N)
{
    __shared__ float T[64][68];
    const int tid = threadIdx.x;
    const int r = tid >> 4, c4 = (tid & 15) * 4;
    const int n0 = blockIdx.x * 64, c0 = blockIdx.y * 64;
    const size_t ib = (size_t)blockIdx.z * C * N;
    const size_t ob = (size_t)blockIdx.z * N * C;
    #pragma unroll
    for (int p = 0; p < 4; ++p) {
        const int cl = r + p * 16;
        const float4 v = *(const float4*)&IN[ib + (size_t)(c0 + cl) * N + n0 + c4];
        *(float4*)&T[cl][c4] = v;
    }
    __syncthreads();
    #pragma unroll
    for (int p = 0; p < 4; ++p) {
        const int nl = r + p * 16;
        ushort4 u;
        u.x = f2bf(T[c4 + 0][nl]);
        u.y = f2bf(T[c4 + 1][nl]);
        u.z = f2bf(T[c4 + 2][nl]);
        u.w = f2bf(T[c4 + 3][nl]);
        *(ushort4*)&OUTb[ob + (size_t)(n0 + nl) * C + c0 + c4] = u;
    }
}

// ---------------------------------------------------------------------------
// swizzled-LDS MFMA helpers. W LDS layout: [128][128] ushort, element (r,c)
// stored at r*128 + (c ^ ((r&7)<<3)).
__device__ __forceinline__ void stage_wbf(const ushort* __restrict__ Wg,
                                          ushort* Wl, int tid)
{
    #pragma unroll
    for (int it = 0; it < 8; ++it) {
        const int lin = (tid + it * 256) * 8;
        const int r = lin >> 7, c = lin & 127;
        const bf16x8 v = *(const bf16x8*)&Wg[lin];
        *(bf16x8*)&Wl[r * 128 + (c ^ ((r & 7) << 3))] = v;
    }
}

__device__ __forceinline__ void layer8swz(const bf16x8 a[4], const ushort* Wl,
                                          f32x4 acc[8], int l15, int lk8)
{
    const int sx = (l15 & 7) << 3;
    #pragma unroll
    for (int ds = 0; ds < 4; ++ds) {
        const int cb = (ds * 32 + lk8) ^ sx;
        #pragma unroll
        for (int nt = 0; nt < 8; ++nt) {
            const bf16x8 b = *(const bf16x8*)&Wl[(nt * 16 + l15) * 128 + cb];
            acc[nt] = __builtin_amdgcn_mfma_f32_16x16x32_bf16(a[ds], b, acc[nt], 0, 0, 0);
        }
    }
}

template <int ACT>
__device__ __forceinline__ void retile_swz(const f32x4 acc[8], const float bias[8],
                                           ushort* tlw, int l15, int lr4, int lk8,
                                           bf16x8 aout[4])
{
    #pragma unroll
    for (int nt = 0; nt < 8; ++nt)
        #pragma unroll
        for (int j = 0; j < 4; ++j) {
            float v = acc[nt][j] + bias[nt];
            if constexpr (ACT == 1) v = act_lrelu(v);
            if constexpr (ACT == 2) v = act_gelu(v);
            const int row = lr4 + j;
            tlw[row * 128 + ((nt * 16 + l15) ^ ((row & 7) << 3))] = f2bf(v);
        }
    const int sx = (l15 & 7) << 3;
    #pragma unroll
    for (int ds = 0; ds < 4; ++ds)
        aout[ds] = *(const bf16x8*)&tlw[l15 * 128 + ((ds * 32 + lk8) ^ sx)];
}

// ---------------------------------------------------------------------------
// wcomb: blocks 0..7: Wcomb_h = wf1_h @ wo via MFMA.
//        blocks 8..11: bconst[j] = bf1[j] + sum_k wf1[j][k]*bo[k&127], 32 j/block.
__global__ __launch_bounds__(256) void wcomb_kernel(
    const ushort* __restrict__ wf1b,   // [128][1024] bf16
    const ushort* __restrict__ woTb,   // [128][128] bf16: woT[d][o]
    const float* __restrict__ wf1, const float* __restrict__ bo,
    const float* __restrict__ bf1,
    ushort* __restrict__ Wcomb, float* __restrict__ bconst)
{
    __shared__ ushort Wl[128 * 128];
    __shared__ float sm[256];
    const int tid = threadIdx.x, lane = tid & 63, w = tid >> 6;
    const int l15 = lane & 15, lk8 = (lane >> 4) * 8, lr4 = (lane >> 4) * 4;
    const int blk = blockIdx.x;
    if (blk < 8) {
        stage_wbf(woTb, Wl, tid);
        __syncthreads();
        const f32x4 z = {0.f, 0.f, 0.f, 0.f};
        #pragma unroll
        for (int rf = 0; rf < 2; ++rf) {
            const int row = w * 32 + rf * 16;
            bf16x8 a[4];
            #pragma unroll
            for (int ds = 0; ds < 4; ++ds)
                a[ds] = *(const bf16x8*)&wf1b[(size_t)(row + l15) * 1024 + blk * 128 + ds * 32 + lk8];
            f32x4 acc[8];
            #pragma unroll
            for (int i = 0; i < 8; ++i) acc[i] = z;
            layer8swz(a, Wl, acc, l15, lk8);
            #pragma unroll
            for (int nt = 0; nt < 8; ++nt)
                #pragma unroll
                for (int j = 0; j < 4; ++j)
                    Wcomb[blk * 16384 + (row + lr4 + j) * 128 + nt * 16 + l15] =
                        f2bf(acc[nt][j]);
        }
    } else {
        // parallel bconst: 8 threads per j, 32 independent float4 loads each
        const int jl = tid >> 3, part = tid & 7;
        const int j = (blk - 8) * 32 + jl;
        float4 a4 = {0.f, 0.f, 0.f, 0.f};
        #pragma unroll
        for (int kk = 0; kk < 128; kk += 4) {
            const float4 wv = *(const float4*)&wf1[(size_t)j * 1024 + part * 128 + kk];
            const float4 bv = *(const float4*)&bo[kk];
            a4.x += wv.x * bv.x; a4.y += wv.y * bv.y;
            a4.z += wv.z * bv.z; a4.w += wv.w * bv.w;
        }
        sm[tid] = a4.x + a4.y + a4.z + a4.w;
        __syncthreads();
        if (part == 0) {
            float t = bf1[j];
            #pragma unroll
            for (int p2 = 0; p2 < 8; ++p2) t += sm[jl * 8 + p2];
            bconst[j] = t;
        }
    }
}

// ---------------------------------------------------------------------------
// mlp1: Y = X @ W_head^T + B_head (no act). 128 rows/block.
template <bool QMAP>
__global__ __launch_bounds__(256) void mlp1v(
    const ushort* __restrict__ X, const ushort* __restrict__ Wbf,
    const float* __restrict__ Bf, ushort* __restrict__ Y)
{
    __shared__ ushort Wl[128 * 128];
    const int tid = threadIdx.x, lane = tid & 63, w = tid >> 6;
    const int l15 = lane & 15, lk8 = (lane >> 4) * 8, lr4 = (lane >> 4) * 4;
    const int head = (blockIdx.x >> 3) & 7;
    stage_wbf(Wbf + head * 16384, Wl, tid);
    float b0[8];
    #pragma unroll
    for (int nt = 0; nt < 8; ++nt) b0[nt] = Bf[head * 128 + nt * 16 + l15];

    const int m0 = blockIdx.x * 128 + w * 32;
    bf16x8 a0[4], a1[4];
    #pragma unroll
    for (int ds = 0; ds < 4; ++ds) {
        int r0 = m0 + l15, r1 = m0 + 16 + l15;
        if constexpr (QMAP) { r0 = (r0 >> 13) * 1024 + (r0 & 1023); r1 = (r1 >> 13) * 1024 + (r1 & 1023); }
        a0[ds] = *(const bf16x8*)(X + (size_t)r0 * 128 + ds * 32 + lk8);
        a1[ds] = *(const bf16x8*)(X + (size_t)r1 * 128 + ds * 32 + lk8);
    }
    __syncthreads();
    const f32x4 z = {0.f, 0.f, 0.f, 0.f};
    #pragma unroll
    for (int rf = 0; rf < 2; ++rf) {
        f32x4 acc[8];
        #pragma unroll
        for (int i = 0; i < 8; ++i) acc[i] = z;
        layer8swz(rf ? a1 : a0, Wl, acc, l15, lk8);
        const int row = m0 + rf * 16;
        #pragma unroll
        for (int nt = 0; nt < 8; ++nt)
            #pragma unroll
            for (int j = 0; j < 4; ++j)
                Y[(size_t)(row + lr4 + j) * 128 + nt * 16 + l15] = f2bf(acc[nt][j] + b0[nt]);
    }
}

// ---------------------------------------------------------------------------
// mlp2: Y = act2(act1(X@W1^T+b1)@W2^T+b2). 128 rows/block. bf16 weights.
template <int ACT1, int ACT2, bool OUTT>
__global__ __launch_bounds__(256) void mlp2v(
    const ushort* __restrict__ X,
    const ushort* __restrict__ W1bf, const float* __restrict__ B1,
    const ushort* __restrict__ W2bf, const float* __restrict__ B2,
    ushort* __restrict__ Y)
{
    __shared__ ushort W1l[128 * 128], W2l[128 * 128];
    __shared__ ushort tl[4][16 * 128];
    const int tid = threadIdx.x, lane = tid & 63, w = tid >> 6;
    const int l15 = lane & 15, lk8 = (lane >> 4) * 8, lr4 = (lane >> 4) * 4;
    stage_wbf(W1bf, W1l, tid);
    stage_wbf(W2bf, W2l, tid);
    float b1[8], b2[8];
    #pragma unroll
    for (int nt = 0; nt < 8; ++nt) { b1[nt] = B1[nt * 16 + l15]; b2[nt] = B2[nt * 16 + l15]; }

    const int m0 = blockIdx.x * 128 + w * 32;
    bf16x8 a0[4], a1[4];
    #pragma unroll
    for (int ds = 0; ds < 4; ++ds) {
        a0[ds] = *(const bf16x8*)(X + (size_t)(m0 + l15) * 128 + ds * 32 + lk8);
        a1[ds] = *(const bf16x8*)(X + (size_t)(m0 + 16 + l15) * 128 + ds * 32 + lk8);
    }
    __syncthreads();
    const f32x4 z = {0.f, 0.f, 0.f, 0.f};
    #pragma unroll
    for (int rf = 0; rf < 2; ++rf) {
        const int row = m0 + rf * 16;
        f32x4 acc[8];
        #pragma unroll
        for (int i = 0; i < 8; ++i) acc[i] = z;
        layer8swz(rf ? a1 : a0, W1l, acc, l15, lk8);
        bf16x8 a2[4];
        retile_swz<ACT1>(acc, b1, tl[w], l15, lr4, lk8, a2);
        f32x4 acc2[8];
        #pragma unroll
        for (int i = 0; i < 8; ++i) acc2[i] = z;
        layer8swz(a2, W2l, acc2, l15, lk8);
        if constexpr (!OUTT) {
            #pragma unroll
            for (int nt = 0; nt < 8; ++nt)
                #pragma unroll
                for (int j = 0; j < 4; ++j) {
                    float v = acc2[nt][j] + b2[nt];
                    if constexpr (ACT2 == 1) v = act_lrelu(v);
                    if constexpr (ACT2 == 2) v = act_gelu(v);
                    Y[(size_t)(row + lr4 + j) * 128 + nt * 16 + l15] = f2bf(v);
                }
        } else {
            const int R0 = row + lr4;
            const int bh = R0 >> 11, key = R0 & 2047;
            #pragma unroll
            for (int nt = 0; nt < 8; ++nt) {
                ushort4 pk;
                #pragma unroll
                for (int j = 0; j < 4; ++j) {
                    float v = acc2[nt][j] + b2[nt];
                    if constexpr (ACT2 == 1) v = act_lrelu(v);
                    if constexpr (ACT2 == 2) v = act_gelu(v);
                    (&pk.x)[j] = f2bf(v);
                }
                *(ushort4*)&Y[((size_t)bh * 128 + nt * 16 + l15) * 2048 + key] = pk;
            }
        }
    }
}

// ---------------------------------------------------------------------------
// outpath: y = lrelu(sum_h enh_h @ Wcomb_h^T + bconst); out = lrelu(y@wf2^T+bf2)
// grid 128 (b*32 + mtile of 32 rows), block 128 (2 waves x 16 rows).
// Wcomb staging is async-split: issue h+1 loads before layer8(h), write after.
__global__ __launch_bounds__(128) void outpath2(
    const ushort* __restrict__ E, const ushort* __restrict__ Wcomb,
    const float* __restrict__ bconst, const ushort* __restrict__ Wf2bf,
    const float* __restrict__ Bf2, float* __restrict__ OUT)
{
    __shared__ ushort Wc[128 * 128], W2l[128 * 128];
    __shared__ ushort tl[2][16 * 128];
    const int tid = threadIdx.x, lane = tid & 63, w = tid >> 6;   // w in {0,1}
    const int l15 = lane & 15, lk8 = (lane >> 4) * 8, lr4 = (lane >> 4) * 4;
    const int b = blockIdx.x >> 5;
    const int m0 = (blockIdx.x & 31) * 32;

    #pragma unroll
    for (int it = 0; it < 16; ++it) {   // stage wf2 (128 threads)
        const int lin = (tid + it * 128) * 8;
        const int r = lin >> 7, c = lin & 127;
        *(bf16x8*)&W2l[r * 128 + (c ^ ((r & 7) << 3))] = *(const bf16x8*)&Wf2bf[lin];
    }
    float bc[8], b2[8];
    #pragma unroll
    for (int nt = 0; nt < 8; ++nt) { bc[nt] = bconst[nt * 16 + l15]; b2[nt] = Bf2[nt * 16 + l15]; }

    const f32x4 z = {0.f, 0.f, 0.f, 0.f};
    f32x4 yacc[8];
    #pragma unroll
    for (int i = 0; i < 8; ++i) yacc[i] = z;

    bf16x8 a[4], an[4], wreg[16];
    auto loadE = [&](int h, bf16x8 dst[4]) {
        const size_t er = ((size_t)((b * 8 + h) * 1024) + m0 + w * 16 + l15) * 128;
        #pragma unroll
        for (int ds = 0; ds < 4; ++ds) dst[ds] = *(const bf16x8*)(E + er + ds * 32 + lk8);
    };
    auto wload = [&](int h) {
        #pragma unroll
        for (int it = 0; it < 16; ++it)
            wreg[it] = *(const bf16x8*)&Wcomb[h * 16384 + (tid + it * 128) * 8];
    };
    auto wwrite = [&]() {
        #pragma unroll
        for (int it = 0; it < 16; ++it) {
            const int lin = (tid + it * 128) * 8;
            const int r = lin >> 7, c = lin & 127;
            *(bf16x8*)&Wc[r * 128 + (c ^ ((r & 7) << 3))] = wreg[it];
        }
    };

    wload(0); wwrite();
    loadE(0, a);
    for (int h = 0; h < 8; ++h) {
        if (h < 7) { wload(h + 1); loadE(h + 1, an); }   // overlap with layer8
        __syncthreads();                                  // Wc writes visible
        layer8swz(a, Wc, yacc, l15, lk8);
        __syncthreads();                                  // Wc reads done
        if (h < 7) {
            wwrite();
            #pragma unroll
            for (int ds = 0; ds < 4; ++ds) a[ds] = an[ds];
        }
    }
    bf16x8 a3[4];
    retile_swz<1>(yacc, bc, tl[w], l15, lr4, lk8, a3);
    f32x4 oacc[8];
    #pragma unroll
    for (int i = 0; i < 8; ++i) oacc[i] = z;
    layer8swz(a3, W2l, oacc, l15, lk8);
    #pragma unroll
    for (int nt = 0; nt < 8; ++nt)
        #pragma unroll
        for (int j = 0; j < 4; ++j)
            OUT[((size_t)b * 1024 + m0 + w * 16 + lr4 + j) * 128 + nt * 16 + l15] =
                act_lrelu(oacc[nt][j] + b2[nt]);
}

// ---------------------------------------------------------------------------
// bf16 MFMA flash attention. 1-D grid 512, XCD-aware decode:
// xcd = bid&7 owns bh in [xcd*4, xcd*4+4); defer-rescale (T13, THR=8).
__global__ __launch_bounds__(256, 2) void flash_attn_bf16(
    const ushort* __restrict__ Q, const ushort* __restrict__ Kx,
    const ushort* __restrict__ Vt, ushort* __restrict__ O)
{
    constexpr float SCALE = 0.08838834764831845f;
    const int bid = blockIdx.x;
    const int bh = (bid & 7) * 4 + ((bid >> 3) & 3);
    const int m0 = (bid >> 5) * 64;
    const int tid = threadIdx.x;
    const int lane = tid & 63, w = tid >> 6;
    const int l15 = lane & 15, lk8 = (lane >> 4) * 8, lr4 = (lane >> 4) * 4;

    __shared__ ushort K_lds[2][64 * 136];
    __shared__ ushort V_lds[2][128 * 72];
    __shared__ ushort P_lds[64 * 72];

    const ushort* Qb = Q + (size_t)bh * 1024 * 128;
    const ushort* Kb = Kx + (size_t)bh * 2048 * 128;
    const ushort* Vb = Vt + (size_t)bh * 128 * 2048;

    bf16x8 qf[4];
    {
        const int row = m0 + w * 16 + l15;
        #pragma unroll
        for (int ds = 0; ds < 4; ++ds)
            qf[ds] = *(const bf16x8*)(Qb + (size_t)row * 128 + ds * 32 + lk8);
    }

    const int kr = tid >> 4, kc = (tid & 15) * 8;
    const int vr = tid >> 3, vc = (tid & 7) * 8;
    bf16x8 kreg[4], vreg[4];
    #pragma unroll
    for (int it = 0; it < 4; ++it) {
        kreg[it] = *(const bf16x8*)(Kb + (size_t)(kr + it * 16) * 128 + kc);
        vreg[it] = *(const bf16x8*)(Vb + (size_t)(vr + it * 32) * 2048 + vc);
    }
    #pragma unroll
    for (int it = 0; it < 4; ++it) {
        *(bf16x8*)&K_lds[0][(kr + it * 16) * 136 + kc] = kreg[it];
        *(bf16x8*)&V_lds[0][(vr + it * 32) * 72 + vc] = vreg[it];
    }
    __syncthreads();

    f32x4 oacc[8];
    #pragma unroll
    for (int i = 0; i < 8; ++i) oacc[i] = f32x4{0.f, 0.f, 0.f, 0.f};
    float mrun[4] = {-1e30f, -1e30f, -1e30f, -1e30f};
    float lrun[4] = {0.f, 0.f, 0.f, 0.f};
    int cur = 0;

    for (int nt = 0; nt < 32; ++nt) {
        if (nt < 31) {
            const int n1 = (nt + 1) * 64;
            #pragma unroll
            for (int it = 0; it < 4; ++it) {
                kreg[it] = *(const bf16x8*)(Kb + (size_t)(n1 + kr + it * 16) * 128 + kc);
                vreg[it] = *(const bf16x8*)(Vb + (size_t)(vr + it * 32) * 2048 + n1 + vc);
            }
        }
        const ushort* Kc = &K_lds[cur][0];
        const ushort* Vc = &V_lds[cur][0];

        f32x4 s[4];
        #pragma unroll
        for (int i = 0; i < 4; ++i) s[i] = f32x4{0.f, 0.f, 0.f, 0.f};
        __builtin_amdgcn_s_setprio(1);
        #pragma unroll
        for (int ds = 0; ds < 4; ++ds)
            #pragma unroll
            for (int ct = 0; ct < 4; ++ct) {
                const bf16x8 bfr = *(const bf16x8*)&Kc[(ct * 16 + l15) * 136 + ds * 32 + lk8];
                s[ct] = __builtin_amdgcn_mfma_f32_16x16x32_bf16(qf[ds], bfr, s[ct], 0, 0, 0);
            }
        __builtin_amdgcn_s_setprio(0);

        // chunk max per row (e-domain)
        float mx[4], p[4][4];
        #pragma unroll
        for (int j = 0; j < 4; ++j)
            mx[j] = fmaxf(fmaxf(s[0][j], s[1][j]), fmaxf(s[2][j], s[3][j])) * SCALE;
        #pragma unroll
        for (int off = 1; off <= 8; off <<= 1)
            #pragma unroll
            for (int j = 0; j < 4; ++j)
                mx[j] = fmaxf(mx[j], __shfl_xor(mx[j], off));

        // defer-rescale (T13): only rescale when max grows by more than THR=8
        const bool within = (mx[0] <= mrun[0] + 8.f) && (mx[1] <= mrun[1] + 8.f) &&
                            (mx[2] <= mrun[2] + 8.f) && (mx[3] <= mrun[3] + 8.f);
        if (!__all((int)within)) {
            float fsc[4];
            #pragma unroll
            for (int j = 0; j < 4; ++j) {
                const float mnew = fmaxf(mrun[j], mx[j]);
                fsc[j] = __expf(mrun[j] - mnew);
                mrun[j] = mnew;
                lrun[j] *= fsc[j];
            }
            #pragma unroll
            for (int dt = 0; dt < 8; ++dt)
                #pragma unroll
                for (int j = 0; j < 4; ++j)
                    oacc[dt][j] *= fsc[j];
        }
        #pragma unroll
        for (int j = 0; j < 4; ++j) {
            float sum = 0.f;
            #pragma unroll
            for (int ct = 0; ct < 4; ++ct) {
                const float e = __expf(s[ct][j] * SCALE - mrun[j]);
                p[ct][j] = e;
                sum += e;
            }
            sum += __shfl_xor(sum, 1); sum += __shfl_xor(sum, 2);
            sum += __shfl_xor(sum, 4); sum += __shfl_xor(sum, 8);
            lrun[j] += sum;
        }
        #pragma unroll
        for (int j = 0; j < 4; ++j) {
            const int prow = w * 16 + lr4 + j;
            #pragma unroll
            for (int ct = 0; ct < 4; ++ct)
                P_lds[prow * 72 + ct * 16 + l15] = f2bf(p[ct][j]);
        }

        __builtin_amdgcn_s_setprio(1);
        #pragma unroll
        for (int ks = 0; ks < 2; ++ks) {
            const bf16x8 pa = *(const bf16x8*)&P_lds[(w * 16 + l15) * 72 + ks * 32 + lk8];
            #pragma unroll
            for (int dt = 0; dt < 8; ++dt) {
                const bf16x8 vb = *(const bf16x8*)&Vc[(dt * 16 + l15) * 72 + ks * 32 + lk8];
                oacc[dt] = __builtin_amdgcn_mfma_f32_16x16x32_bf16(pa, vb, oacc[dt], 0, 0, 0);
            }
        }
        __builtin_amdgcn_s_setprio(0);

        if (nt < 31) {
            const int nxt = cur ^ 1;
            #pragma unroll
            for (int it = 0; it < 4; ++it) {
                *(bf16x8*)&K_lds[nxt][(kr + it * 16) * 136 + kc] = kreg[it];
                *(bf16x8*)&V_lds[nxt][(vr + it * 32) * 72 + vc] = vreg[it];
            }
        }
        __syncthreads();
        cur ^= 1;
    }

    ushort* Ob = O + (size_t)bh * 1024 * 128;
    #pragma unroll
    for (int j = 0; j < 4; ++j) {
        const float inv = 1.0f / lrun[j];
        const int row = m0 + w * 16 + lr4 + j;
        #pragma unroll
        for (int dt = 0; dt < 8; ++dt)
            Ob[(size_t)row * 128 + dt * 16 + l15] = f2bf(oacc[dt][j] * inv);
    }
}

// ---------------------------------------------------------------------------
extern "C" void kernel_launch(void* const* d_in, const int* in_sizes, int n_in,
                              void* d_out, int out_size, void* d_ws, size_t ws_size,
                              hipStream_t stream)
{
    (void)in_sizes; (void)n_in; (void)out_size; (void)ws_size;
    const float* query = (const float*)d_in[0];
    const float* fts   = (const float*)d_in[1];
    const float* wqc = (const float*)d_in[2];
    const float* bqc = (const float*)d_in[3];
    const float* wq1 = (const float*)d_in[4];
    const float* bq1 = (const float*)d_in[5];
    const float* wq2 = (const float*)d_in[6];
    const float* bq2 = (const float*)d_in[7];
    const float* wk1 = (const float*)d_in[8];
    const float* bk1 = (const float*)d_in[9];
    const float* wk2 = (const float*)d_in[10];
    const float* bk2 = (const float*)d_in[11];
    const float* wv1 = (const float*)d_in[12];
    const float* bv1 = (const float*)d_in[13];
    const float* wv2 = (const float*)d_in[14];
    const float* bv2 = (const float*)d_in[15];
    const float* wo  = (const float*)d_in[16];
    const float* bo  = (const float*)d_in[17];
    const float* wf1 = (const float*)d_in[18];
    const float* bf1 = (const float*)d_in[19];
    const float* wf2 = (const float*)d_in[20];
    const float* bf2 = (const float*)d_in[21];
    float* out = (float*)d_out;

    // ws layout (~78 MB)
    char* ws = (char*)d_ws;
    ushort* ftb    = (ushort*)(ws + 0LL);          // 16 MB [32][2048][128]
    ushort* queryT = (ushort*)(ws + 16777216LL);   //  1 MB [4][1024][128]
    ushort* qh     = (ushort*)(ws + 17825792LL);   //  8 MB [32][1024][128]
    ushort* qbuf   = (ushort*)(ws + 26214400LL);   //  8 MB [32][1024][128]
    ushort* kbuf   = (ushort*)(ws + 34603008LL);   // 16 MB [32][2048][128]
    ushort* vbufT  = (ushort*)(ws + 51380224LL);   // 16 MB [32][128][2048]
    ushort* enh    = (ushort*)(ws + 68157440LL);   //  8 MB [32][1024][128]
    ushort* Wbf    = (ushort*)(ws + 76546048LL);   // 736 KB converted weights (incl wf1)
    ushort* Wcomb  = (ushort*)(ws + 77299712LL);   // 256 KB [8][128][128]
    float*  bconst = (float*) (ws + 77561856LL);   // 512 B
    ushort* woTb   = (ushort*)(ws + 77562368LL);   // 32 KB [128][128]

    // bf16 weight sub-offsets (ushort units)
    ushort* wqc_b = Wbf + 0;
    ushort* wq1_b = Wbf + 131072;
    ushort* wq2_b = Wbf + 147456;
    ushort* wk1_b = Wbf + 163840;
    ushort* wk2_b = Wbf + 180224;
    ushort* wv1_b = Wbf + 196608;
    ushort* wv2_b = Wbf + 212992;
    ushort* wf2_b = Wbf + 229376;
    ushort* wf1_b = Wbf + 245760;

    convert_kernel<<<92, 256, 0, stream>>>(wqc, wq1, wq2, wk1, wk2, wv1, wv2,
                                           wf2, wf1, Wbf);
    transpose_cast<<<dim3(2, 2, 1), 256, 0, stream>>>(wo, woTb, 128, 128);
    wcomb_kernel<<<12, 256, 0, stream>>>(wf1_b, woTb, wf1, bo, bf1, Wcomb, bconst);
    transpose_cast<<<dim3(32, 2, 32), 256, 0, stream>>>(fts, ftb, 128, 2048);
    transpose_cast<<<dim3(16, 2, 4), 256, 0, stream>>>(query, queryT, 128, 1024);
    // q-path
    mlp1v<true><<<256, 256, 0, stream>>>(queryT, wqc_b, bqc, qh);
    mlp2v<1, 2, false><<<256, 256, 0, stream>>>(qh, wq1_b, bq1, wq2_b, bq2, qbuf);
    // k-path / v-path
    mlp2v<1, 2, false><<<512, 256, 0, stream>>>(ftb, wk1_b, bk1, wk2_b, bk2, kbuf);
    mlp2v<1, 2, true><<<512, 256, 0, stream>>>(ftb, wv1_b, bv1, wv2_b, bv2, vbufT);
    // attention
    flash_attn_bf16<<<512, 256, 0, stream>>>(qbuf, kbuf, vbufT, enh);
    // fused proj_out+concat+final MLP
    outpath2<<<128, 128, 0, stream>>>(enh, Wcomb, bconst, wf2_b, bf2, out);
}